// Round 4
// baseline (316.054 us; speedup 1.0000x reference)
//
#include <hip/hip_runtime.h>
#include <hip/hip_bf16.h>

#define NEG_INF -1000000000.0f

typedef __attribute__((ext_vector_type(8))) short bf16x8;
typedef __attribute__((ext_vector_type(4))) float f32x4;

__device__ __forceinline__ unsigned short f2bf(float f) {
    unsigned int u = __float_as_uint(f);
    u += 0x7FFFu + ((u >> 16) & 1u);
    return (unsigned short)(u >> 16);
}

#define GLOAD_LDS16(gp, lp)                                                  \
    __builtin_amdgcn_global_load_lds(                                        \
        (const __attribute__((address_space(1))) void*)(gp),                 \
        (__attribute__((address_space(3))) void*)(lp), 16, 0, 0)

#define SCHED0 __builtin_amdgcn_sched_barrier(0)
#define BARX() do { SCHED0; __builtin_amdgcn_s_barrier(); SCHED0; } while (0)

// 256x256-tile BT-form bf16 GEMM, BK=64, 512 threads = 8 waves (2Mx4N).
// 4 regions per K-tile, ONE barrier per region; A-quad ds_reads pipelined one
// region ahead so reads overlap MFMA within the region. Double-buffered LDS,
// counted-vmcnt (never 0 in main loop), T2 XOR swizzle, T5 setprio.
// C[m][n] = sum_k A[m][k]*B[n][k].
// EPI: 0 = projection (bf16 out, +bias, *scale, optional transposed store)
//      1 = scores (fp32 out, mask per column)   2 = plain fp32 out
template<int EPI, bool TRANS>
__global__ __launch_bounds__(512, 2)
void gemm256(const unsigned short* __restrict__ A, const unsigned short* __restrict__ B,
             void* __restrict__ Cp, const float* __restrict__ bias,
             const int* __restrict__ mask,
             int K, long lda, long ldb, long ldc,
             long batchA, long batchB, long batchC, float scale,
             int gx, int gy)
{
    __shared__ unsigned short As[2][16384];
    __shared__ unsigned short Bs[2][16384];

    // T1: bijective XCD swizzle (all launches have nwg % 8 == 0)
    int bid = blockIdx.x;
    bid = (bid & 7) * ((int)gridDim.x >> 3) + (bid >> 3);
    const int gxy = gx * gy;
    const int bz  = bid / gxy;
    const int rem = bid - bz * gxy;
    const int tm  = rem / gy;
    const int bm  = tm * 256;
    const int bn  = (rem - tm * gy) * 256;

    const int t    = threadIdx.x;
    const int lane = t & 63;
    const int w    = t >> 6;
    const int wr   = w >> 2;          // wave row 0..1 (128 rows each)
    const int wc   = w & 3;           // wave col 0..3 (64 cols each)
    const int lr   = lane & 15;
    const int lkg  = lane >> 4;       // 0..3
    const int sx8  = (lr & 7) * 8;    // T2 read-side XOR (row parity, elems)
    const int e0   = (lkg * 8) ^ sx8; // kk=0 chunk; kk=1 is e0^32

    // staging: thread t -> row tr (of 64-row load region), swizzled col chunk
    const int tr  = t >> 3;
    const int tcs = ((t & 7) ^ (tr & 7)) * 8;    // pre-swizzled source col (elems)
    const int wb512 = w * 512;                   // wave-uniform LDS elem offset

    const unsigned short* Ab = A + (size_t)bz * (size_t)batchA + (size_t)(bm + tr) * lda + tcs;
    const unsigned short* Bb = B + (size_t)bz * (size_t)batchB + (size_t)(bn + tr) * ldb + tcs;

#define ST_A(nb, L, kt) GLOAD_LDS16(Ab + (size_t)(L) * 64 * lda + (kt), &As[nb][(L) * 4096 + wb512])
#define ST_B(nb, L, kt) GLOAD_LDS16(Bb + (size_t)(L) * 64 * ldb + (kt), &Bs[nb][(L) * 4096 + wb512])

    f32x4 acc[8][4];
#pragma unroll
    for (int i = 0; i < 8; ++i)
#pragma unroll
        for (int j = 0; j < 4; ++j)
            acc[i][j] = f32x4{0.f, 0.f, 0.f, 0.f};

    // ---- prologue: stage tile 0 (needed-first order), leave A1,A3 in flight ----
    ST_B(0, 0, 0); ST_B(0, 1, 0); ST_B(0, 2, 0); ST_B(0, 3, 0);
    ST_A(0, 0, 0); ST_A(0, 2, 0); ST_A(0, 1, 0); ST_A(0, 3, 0);
    asm volatile("s_waitcnt vmcnt(2)" ::: "memory");
    BARX();

    bf16x8 aA[2][2], aB[2][2], b[4][2];

#define READ_B(BUF)                                                          \
    _Pragma("unroll") for (int j = 0; j < 4; ++j) {                          \
        const int Rb = wc * 64 + j * 16 + lr;                                \
        b[j][0] = *(const bf16x8*)&Bs[BUF][Rb * 64 + e0];                    \
        b[j][1] = *(const bf16x8*)&Bs[BUF][Rb * 64 + (e0 ^ 32)];             \
    }

#define READ_AQ(dst, BUF, qp)                                                \
    _Pragma("unroll") for (int i2 = 0; i2 < 2; ++i2) {                       \
        const int Ra = wr * 128 + (qp) * 32 + i2 * 16 + lr;                  \
        dst[i2][0] = *(const bf16x8*)&As[BUF][Ra * 64 + e0];                 \
        dst[i2][1] = *(const bf16x8*)&As[BUF][Ra * 64 + (e0 ^ 32)];          \
    }

#define MFMA_Q(qp, src)                                                      \
    __builtin_amdgcn_s_setprio(1);                                           \
    _Pragma("unroll") for (int kk = 0; kk < 2; ++kk)                         \
    _Pragma("unroll") for (int i2 = 0; i2 < 2; ++i2)                         \
    _Pragma("unroll") for (int j = 0; j < 4; ++j)                            \
        acc[(qp) * 2 + i2][j] = __builtin_amdgcn_mfma_f32_16x16x32_bf16(     \
            src[i2][kk], b[j][kk], acc[(qp) * 2 + i2][j], 0, 0, 0);          \
    __builtin_amdgcn_s_setprio(0);

#define TILE(BUF, STAGE, ktn)                                                \
    {                                                                        \
        const int buf_ = (BUF); const int nb_ = buf_ ^ 1;                    \
        /* R0: B frags + A quads 0,1 (L0/L2 region, landed); MFMA quad0 */   \
        READ_B(buf_)                                                         \
        READ_AQ(aA, buf_, 0)                                                 \
        if (STAGE) { ST_B(nb_, 0, ktn); ST_B(nb_, 1, ktn); }                 \
        READ_AQ(aB, buf_, 1)                                                 \
        MFMA_Q(0, aA)                                                        \
        BARX();                                                              \
        /* R1: MFMA quad1; then drain A1,A3 of this tile; read quad2 */      \
        if (STAGE) { ST_B(nb_, 2, ktn); ST_B(nb_, 3, ktn); }                 \
        MFMA_Q(1, aB)                                                        \
        if (STAGE) { asm volatile("s_waitcnt vmcnt(4)" ::: "memory"); }      \
        else       { asm volatile("s_waitcnt vmcnt(0)" ::: "memory"); }      \
        SCHED0;                                                              \
        READ_AQ(aA, buf_, 2)                                                 \
        BARX();                                                              \
        /* R2: read quad3 ahead; MFMA quad2 */                               \
        if (STAGE) { ST_A(nb_, 0, ktn); ST_A(nb_, 2, ktn); }                 \
        READ_AQ(aB, buf_, 3)                                                 \
        MFMA_Q(2, aA)                                                        \
        BARX();                                                              \
        /* R3: MFMA quad3; boundary wait leaves A1,A3 of next in flight */   \
        if (STAGE) { ST_A(nb_, 1, ktn); ST_A(nb_, 3, ktn); }                 \
        MFMA_Q(3, aB)                                                        \
        if (STAGE) { asm volatile("s_waitcnt vmcnt(2)" ::: "memory"); }      \
        BARX();                                                              \
    }

    const int NT = K >> 6;
    for (int k = 0; k < NT - 1; ++k) {
        TILE(k & 1, true, (k + 1) << 6);
    }
    TILE((NT - 1) & 1, false, 0);

#undef TILE
#undef MFMA_Q
#undef READ_AQ
#undef READ_B
#undef ST_A
#undef ST_B

    // ---- epilogue ----  C/D: col = lane&15 (lr), row = lkg*4 + reg
    const int r0 = lkg * 4;
    const size_t coff = (size_t)bz * (size_t)batchC;
#pragma unroll
    for (int ri = 0; ri < 8; ++ri) {
#pragma unroll
        for (int j = 0; j < 4; ++j) {
            const int gcol = bn + wc * 64 + j * 16 + lr;
            if (EPI == 0) {
                const float bv = bias[gcol];
                if (TRANS) {
                    const int m0 = bm + wr * 128 + ri * 16 + r0;
                    const int bb = m0 >> 11;
                    const int s0 = m0 & 2047;
                    ushort4 wv;
                    wv.x = f2bf((acc[ri][j][0] + bv) * scale);
                    wv.y = f2bf((acc[ri][j][1] + bv) * scale);
                    wv.z = f2bf((acc[ri][j][2] + bv) * scale);
                    wv.w = f2bf((acc[ri][j][3] + bv) * scale);
                    *(ushort4*)((unsigned short*)Cp + (size_t)bb * (1024 * 2048)
                                + (size_t)gcol * 2048 + s0) = wv;
                } else {
#pragma unroll
                    for (int r = 0; r < 4; ++r) {
                        const int grow = bm + wr * 128 + ri * 16 + r0 + r;
                        ((unsigned short*)Cp)[(size_t)grow * ldc + gcol] =
                            f2bf((acc[ri][j][r] + bv) * scale);
                    }
                }
            } else if (EPI == 1) {
                const int mv = mask[(size_t)bz * 2048 + gcol];
#pragma unroll
                for (int r = 0; r < 4; ++r) {
                    const int grow = bm + wr * 128 + ri * 16 + r0 + r;
                    float v = acc[ri][j][r];
                    if (mv == 0) v = NEG_INF;
                    ((float*)Cp)[coff + (size_t)grow * ldc + gcol] = v;
                }
            } else {
#pragma unroll
                for (int r = 0; r < 4; ++r) {
                    const int grow = bm + wr * 128 + ri * 16 + r0 + r;
                    ((float*)Cp)[coff + (size_t)grow * ldc + gcol] = acc[ri][j][r];
                }
            }
        }
    }
}

// fp32 -> bf16 conversion, 4 elems/thread
__global__ __launch_bounds__(256)
void conv_f32_bf16(const float4* __restrict__ src, ushort4* __restrict__ dst, int n4)
{
    const int i = blockIdx.x * 256 + threadIdx.x;
    if (i < n4) {
        const float4 v = src[i];
        ushort4 wv;
        wv.x = f2bf(v.x); wv.y = f2bf(v.y); wv.z = f2bf(v.z); wv.w = f2bf(v.w);
        dst[i] = wv;
    }
}

// Row softmax over 2048 fp32 scores; writes P as bf16 in-place into the low
// half of the row's storage (row stride stays 4096 bf16 elems).
__global__ __launch_bounds__(256)
void softmax_rows(float* __restrict__ S)
{
    const size_t row = blockIdx.x;
    float* sr = S + row * 2048;
    const int t = threadIdx.x;

    const float4 v0 = *(const float4*)&sr[t * 8];
    const float4 v1 = *(const float4*)&sr[t * 8 + 4];

    float m = fmaxf(fmaxf(fmaxf(v0.x, v0.y), fmaxf(v0.z, v0.w)),
                    fmaxf(fmaxf(v1.x, v1.y), fmaxf(v1.z, v1.w)));

    __shared__ float red[256];
    red[t] = m;
    __syncthreads();
    for (int s = 128; s > 0; s >>= 1) {
        if (t < s) red[t] = fmaxf(red[t], red[t + s]);
        __syncthreads();
    }
    const float mx = red[0];
    __syncthreads();

    float e[8];
    e[0] = __expf(v0.x - mx); e[1] = __expf(v0.y - mx);
    e[2] = __expf(v0.z - mx); e[3] = __expf(v0.w - mx);
    e[4] = __expf(v1.x - mx); e[5] = __expf(v1.y - mx);
    e[6] = __expf(v1.z - mx); e[7] = __expf(v1.w - mx);
    float s8 = ((e[0] + e[1]) + (e[2] + e[3])) + ((e[4] + e[5]) + (e[6] + e[7]));

    red[t] = s8;
    __syncthreads();
    for (int s = 128; s > 0; s >>= 1) {
        if (t < s) red[t] += red[t + s];
        __syncthreads();
    }
    const float inv = 1.0f / red[0];

    unsigned short* pr = (unsigned short*)sr;
    ushort4 w0, w1;
    w0.x = f2bf(e[0] * inv); w0.y = f2bf(e[1] * inv);
    w0.z = f2bf(e[2] * inv); w0.w = f2bf(e[3] * inv);
    w1.x = f2bf(e[4] * inv); w1.y = f2bf(e[5] * inv);
    w1.z = f2bf(e[6] * inv); w1.w = f2bf(e[7] * inv);
    *(ushort4*)&pr[t * 8]     = w0;
    *(ushort4*)&pr[t * 8 + 4] = w1;
}

extern "C" void kernel_launch(void* const* d_in, const int* in_sizes, int n_in,
                              void* d_out, int out_size, void* d_ws, size_t ws_size,
                              hipStream_t stream)
{
    const float* x    = (const float*)d_in[0];
    const int*   mask = (const int*)d_in[1];
    const float* Wq   = (const float*)d_in[2];
    const float* bq   = (const float*)d_in[3];
    const float* Wk   = (const float*)d_in[4];
    const float* bk   = (const float*)d_in[5];
    const float* Wv   = (const float*)d_in[6];
    const float* bv   = (const float*)d_in[7];
    float* out = (float*)d_out;

    char* ws = (char*)d_ws;
    unsigned short* Q  = (unsigned short*)(ws);                  // [8][2048][1024] bf16, pre-scaled 1/32
    unsigned short* Kt = (unsigned short*)(ws + (32ull << 20));  // [8][2048][1024] bf16
    unsigned short* Vt = (unsigned short*)(ws + (64ull << 20));  // [8][1024][2048] bf16 (transposed)
    float*          Sm = (float*)(ws + (96ull << 20));           // [8][2048][2048] fp32 -> P bf16 in-place
    unsigned short* xb = (unsigned short*)(ws + (96ull << 20));  // bf16 x (dead after projections)
    unsigned short* wb = (unsigned short*)(ws + (128ull << 20)); // bf16 weights

    const int D = 1024, S = 2048, B = 8, Mtot = 16384;
    dim3 blk2(256), blk5(512);

    // ---- fp32 -> bf16 conversions ----
    conv_f32_bf16<<<dim3((Mtot * D / 4) / 256), blk2, 0, stream>>>((const float4*)x, (ushort4*)xb, Mtot * D / 4);
    conv_f32_bf16<<<dim3((D * D / 4) / 256), blk2, 0, stream>>>((const float4*)Wq, (ushort4*)(wb + 0ull * D * D), D * D / 4);
    conv_f32_bf16<<<dim3((D * D / 4) / 256), blk2, 0, stream>>>((const float4*)Wk, (ushort4*)(wb + 1ull * D * D), D * D / 4);
    conv_f32_bf16<<<dim3((D * D / 4) / 256), blk2, 0, stream>>>((const float4*)Wv, (ushort4*)(wb + 2ull * D * D), D * D / 4);

    // ---- QKV projections: C = x @ W^T + b  (grid 64x4 = 256 blocks) ----
    gemm256<0, false><<<dim3(256), blk5, 0, stream>>>(
        xb, wb + 0ull * D * D, Q, bq, nullptr, D, 1024, 1024, 1024, 0, 0, 0, 0.03125f, 64, 4);
    gemm256<0, false><<<dim3(256), blk5, 0, stream>>>(
        xb, wb + 1ull * D * D, Kt, bk, nullptr, D, 1024, 1024, 1024, 0, 0, 0, 1.0f, 64, 4);
    gemm256<0, true><<<dim3(256), blk5, 0, stream>>>(
        xb, wb + 2ull * D * D, Vt, bv, nullptr, D, 1024, 1024, 1024, 0, 0, 0, 1.0f, 64, 4);

    // ---- scores: S_b = Q_b @ K_b^T (scale folded into Q), mask in epilogue ----
    gemm256<1, false><<<dim3(512), blk5, 0, stream>>>(
        Q, Kt, Sm, nullptr, mask, D, 1024, 1024, 2048,
        (long)S * D, (long)S * D, (long)S * S, 1.0f, 8, 8);

    // ---- softmax rows (fp32 in, bf16 P out in-place; P row stride 4096) ----
    softmax_rows<<<dim3(B * S), blk2, 0, stream>>>(Sm);

    // ---- out: O_b = P_b @ V_b = P_b . Vt_b^T ----
    gemm256<2, false><<<dim3(256), blk5, 0, stream>>>(
        (const unsigned short*)Sm, Vt, out, nullptr, nullptr, S, 4096, 2048, 1024,
        (long)S * 4096, (long)D * S, (long)S * D, 1.0f, 8, 4);
}

// Round 6
// 299.917 us; speedup vs baseline: 1.0538x; 1.0538x over previous
//
#include <hip/hip_runtime.h>
#include <hip/hip_bf16.h>
#include <hip/hip_fp16.h>

#define NEG_INF -1000000000.0f

typedef __attribute__((ext_vector_type(8))) short bf16x8;
typedef __attribute__((ext_vector_type(4))) float f32x4;

__device__ __forceinline__ unsigned short f2bf(float f) {
    unsigned int u = __float_as_uint(f);
    u += 0x7FFFu + ((u >> 16) & 1u);
    return (unsigned short)(u >> 16);
}

__device__ __forceinline__ float h2f(unsigned short us) {
    __half h;
    __builtin_memcpy(&h, &us, 2);
    return __half2float(h);
}

#define GLOAD_LDS16(gp, lp)                                                  \
    __builtin_amdgcn_global_load_lds(                                        \
        (const __attribute__((address_space(1))) void*)(gp),                 \
        (__attribute__((address_space(3))) void*)(lp), 16, 0, 0)

// 256x256-tile BT-form bf16 GEMM, BK=64, 512 threads = 8 waves (2Mx4N),
// 4 phases per K-tile (2 barriers/phase), double-buffered 128 KiB LDS,
// counted-vmcnt pipeline (never 0 in main loop), T2 XOR swizzle, T5 setprio.
// C[m][n] = sum_k A[m][k]*B[n][k].
// EPI: 0 = fused QKV projection (N=3072; which=bn>>10: 0->Q(*1/32), 1->K, 2->V transposed)
//      1 = scores (fp16 out, no mask)   2 = plain fp32 out
template<int EPI>
__global__ __launch_bounds__(512, 2)
void gemm256(const unsigned short* __restrict__ A, const unsigned short* __restrict__ B,
             void* __restrict__ C0, void* __restrict__ C1, void* __restrict__ C2,
             const float* __restrict__ b0, const float* __restrict__ b1,
             const float* __restrict__ b2,
             int K, long lda, long ldb, long ldc,
             long batchA, long batchB, long batchC,
             int gx, int gy)
{
    __shared__ unsigned short As[2][16384];
    __shared__ unsigned short Bs[2][16384];

    // T1: bijective XCD swizzle (all launches have nwg % 8 == 0)
    int bid = blockIdx.x;
    bid = (bid & 7) * ((int)gridDim.x >> 3) + (bid >> 3);
    const int gxy = gx * gy;
    const int bz  = bid / gxy;
    const int rem = bid - bz * gxy;
    const int tm  = rem / gy;
    const int bm  = tm * 256;
    const int bn  = (rem - tm * gy) * 256;

    const int t    = threadIdx.x;
    const int lane = t & 63;
    const int w    = t >> 6;
    const int wr   = w >> 2;          // wave row 0..1 (128 rows each)
    const int wc   = w & 3;           // wave col 0..3 (64 cols each)
    const int lr   = lane & 15;
    const int lkg  = lane >> 4;       // 0..3
    const int sx8  = (lr & 7) * 8;    // T2 read-side XOR (row parity, elems)
    const int e0   = (lkg * 8) ^ sx8; // kk=0 chunk; kk=1 is e0^32

    // staging: thread t -> row tr (of 64-row load region), swizzled col chunk
    const int tr  = t >> 3;
    const int tcs = ((t & 7) ^ (tr & 7)) * 8;    // pre-swizzled source col (elems)
    const int wb512 = w * 512;                   // wave-uniform LDS elem offset

    const unsigned short* Ab = A + (size_t)bz * (size_t)batchA + (size_t)(bm + tr) * lda + tcs;
    const unsigned short* Bb = B + (size_t)bz * (size_t)batchB + (size_t)(bn + tr) * ldb + tcs;

#define ST_A(nb, L, kt) GLOAD_LDS16(Ab + (size_t)(L) * 64 * lda + (kt), &As[nb][(L) * 4096 + wb512])
#define ST_B(nb, L, kt) GLOAD_LDS16(Bb + (size_t)(L) * 64 * ldb + (kt), &Bs[nb][(L) * 4096 + wb512])

    f32x4 acc[8][4];
#pragma unroll
    for (int i = 0; i < 8; ++i)
#pragma unroll
        for (int j = 0; j < 4; ++j)
            acc[i][j] = f32x4{0.f, 0.f, 0.f, 0.f};

    // ---- prologue: stage tile 0 (needed-first order), leave A1,A3 in flight ----
    ST_B(0, 0, 0); ST_B(0, 1, 0); ST_B(0, 2, 0); ST_B(0, 3, 0);
    ST_A(0, 0, 0); ST_A(0, 2, 0); ST_A(0, 1, 0); ST_A(0, 3, 0);
    asm volatile("s_waitcnt vmcnt(2)" ::: "memory");
    __builtin_amdgcn_s_barrier();

    bf16x8 a[2][2], b[4][2];

#define READ_B(BUF)                                                          \
    _Pragma("unroll") for (int j = 0; j < 4; ++j) {                          \
        const int Rb = wc * 64 + j * 16 + lr;                                \
        b[j][0] = *(const bf16x8*)&Bs[BUF][Rb * 64 + e0];                    \
        b[j][1] = *(const bf16x8*)&Bs[BUF][Rb * 64 + (e0 ^ 32)];             \
    }

#define LOAD_A(BUF, qp)                                                      \
    _Pragma("unroll") for (int i2 = 0; i2 < 2; ++i2) {                       \
        const int Ra = wr * 128 + (qp) * 32 + i2 * 16 + lr;                  \
        a[i2][0] = *(const bf16x8*)&As[BUF][Ra * 64 + e0];                   \
        a[i2][1] = *(const bf16x8*)&As[BUF][Ra * 64 + (e0 ^ 32)];            \
    }

#define MFMA_Q(qp)                                                           \
    __builtin_amdgcn_s_setprio(1);                                           \
    _Pragma("unroll") for (int kk = 0; kk < 2; ++kk)                         \
    _Pragma("unroll") for (int i2 = 0; i2 < 2; ++i2)                         \
    _Pragma("unroll") for (int j = 0; j < 4; ++j)                            \
        acc[(qp) * 2 + i2][j] = __builtin_amdgcn_mfma_f32_16x16x32_bf16(     \
            a[i2][kk], b[j][kk], acc[(qp) * 2 + i2][j], 0, 0, 0);            \
    __builtin_amdgcn_s_setprio(0);

#define TILE(BUF, STAGE, ktn)                                                \
    {                                                                        \
        const int buf_ = (BUF); const int nb_ = buf_ ^ 1;                    \
        /* phase 0: B-frags (whole tile) + A quad 0; stage B0,B1 of next */  \
        READ_B(buf_)                                                         \
        LOAD_A(buf_, 0)                                                      \
        if (STAGE) { ST_B(nb_, 0, ktn); ST_B(nb_, 1, ktn); }                 \
        __builtin_amdgcn_s_barrier();                                        \
        MFMA_Q(0)                                                            \
        __builtin_amdgcn_s_barrier();                                        \
        /* phase 1 */                                                        \
        LOAD_A(buf_, 1)                                                      \
        if (STAGE) { ST_B(nb_, 2, ktn); ST_B(nb_, 3, ktn); }                 \
        __builtin_amdgcn_s_barrier();                                        \
        MFMA_Q(1)                                                            \
        if (STAGE) { asm volatile("s_waitcnt vmcnt(4)" ::: "memory"); }      \
        else       { asm volatile("s_waitcnt vmcnt(0)" ::: "memory"); }      \
        __builtin_amdgcn_s_barrier();                                        \
        /* phase 2 */                                                        \
        LOAD_A(buf_, 2)                                                      \
        if (STAGE) { ST_A(nb_, 0, ktn); ST_A(nb_, 2, ktn); }                 \
        __builtin_amdgcn_s_barrier();                                        \
        MFMA_Q(2)                                                            \
        __builtin_amdgcn_s_barrier();                                        \
        /* phase 3 */                                                        \
        LOAD_A(buf_, 3)                                                      \
        if (STAGE) { ST_A(nb_, 1, ktn); ST_A(nb_, 3, ktn); }                 \
        __builtin_amdgcn_s_barrier();                                        \
        MFMA_Q(3)                                                            \
        if (STAGE) { asm volatile("s_waitcnt vmcnt(2)" ::: "memory"); }      \
        __builtin_amdgcn_s_barrier();                                        \
    }

    const int NT = K >> 6;
    for (int k = 0; k < NT - 1; ++k) {
        TILE(k & 1, true, (k + 1) << 6);
    }
    TILE((NT - 1) & 1, false, 0);

#undef TILE
#undef MFMA_Q
#undef LOAD_A
#undef READ_B
#undef ST_A
#undef ST_B

    // ---- epilogue ----  C/D: col = lane&15 (lr), row = lkg*4 + reg
    const int r0 = lkg * 4;
    const size_t coff = (size_t)bz * (size_t)batchC;
#pragma unroll
    for (int ri = 0; ri < 8; ++ri) {
#pragma unroll
        for (int j = 0; j < 4; ++j) {
            if (EPI == 0) {
                const int which = bn >> 10;               // block-uniform: 0=Q,1=K,2=V
                const float scl = (which == 0) ? 0.03125f : 1.0f;
                const float* bias = (which == 0) ? b0 : (which == 1 ? b1 : b2);
                unsigned short* dst = (unsigned short*)
                    ((which == 0) ? C0 : (which == 1 ? C1 : C2));
                const int gcol3 = bn + wc * 64 + j * 16 + lr;
                const int col   = gcol3 & 1023;
                const float bv  = bias[col];
                if (which == 2) {
                    // V: store transposed Vt[b][d][s]
                    const int m0 = bm + wr * 128 + ri * 16 + r0;
                    const int bb = m0 >> 11;
                    const int s0 = m0 & 2047;
                    ushort4 wv;
                    wv.x = f2bf(acc[ri][j][0] + bv);
                    wv.y = f2bf(acc[ri][j][1] + bv);
                    wv.z = f2bf(acc[ri][j][2] + bv);
                    wv.w = f2bf(acc[ri][j][3] + bv);
                    *(ushort4*)(dst + (size_t)bb * (1024 * 2048)
                                + (size_t)col * 2048 + s0) = wv;
                } else {
#pragma unroll
                    for (int r = 0; r < 4; ++r) {
                        const int grow = bm + wr * 128 + ri * 16 + r0 + r;
                        dst[(size_t)grow * ldc + col] = f2bf((acc[ri][j][r] + bv) * scl);
                    }
                }
            } else if (EPI == 1) {
                const int gcol = bn + wc * 64 + j * 16 + lr;
#pragma unroll
                for (int r = 0; r < 4; ++r) {
                    const int grow = bm + wr * 128 + ri * 16 + r0 + r;
                    ((__half*)C0)[coff + (size_t)grow * ldc + gcol] =
                        __float2half(acc[ri][j][r]);
                }
            } else {
                const int gcol = bn + wc * 64 + j * 16 + lr;
#pragma unroll
                for (int r = 0; r < 4; ++r) {
                    const int grow = bm + wr * 128 + ri * 16 + r0 + r;
                    ((float*)C0)[coff + (size_t)grow * ldc + gcol] = acc[ri][j][r];
                }
            }
        }
    }
}

// fp32 -> bf16 conversion, 4 elems/thread
__global__ __launch_bounds__(256)
void conv_f32_bf16(const float4* __restrict__ src, ushort4* __restrict__ dst, int n4)
{
    const int i = blockIdx.x * 256 + threadIdx.x;
    if (i < n4) {
        const float4 v = src[i];
        ushort4 wv;
        wv.x = f2bf(v.x); wv.y = f2bf(v.y); wv.z = f2bf(v.z); wv.w = f2bf(v.w);
        dst[i] = wv;
    }
}

// Row softmax: fp16 scores in (raw, unmasked), mask applied here, bf16 P out
// (compact, stride 2048). Masked cols -> s = -1e9 -> exp underflows to 0;
// all-masked row degenerates to uniform 1/2048 (matches reference).
__global__ __launch_bounds__(256)
void softmax_rows(const __half* __restrict__ S, const int* __restrict__ mask,
                  unsigned short* __restrict__ P)
{
    const size_t row = blockIdx.x;          // b*2048 + q
    const int b = (int)(row >> 11);
    const __half* sr = S + row * 2048;
    unsigned short* pr = P + row * 2048;
    const int t = threadIdx.x;

    const ushort4 h0 = *(const ushort4*)&sr[t * 8];
    const ushort4 h1 = *(const ushort4*)&sr[t * 8 + 4];
    const int4 mv0 = *(const int4*)&mask[b * 2048 + t * 8];
    const int4 mv1 = *(const int4*)&mask[b * 2048 + t * 8 + 4];

    float s[8];
    s[0] = h2f(h0.x); s[1] = h2f(h0.y); s[2] = h2f(h0.z); s[3] = h2f(h0.w);
    s[4] = h2f(h1.x); s[5] = h2f(h1.y); s[6] = h2f(h1.z); s[7] = h2f(h1.w);
    if (mv0.x == 0) s[0] = NEG_INF;
    if (mv0.y == 0) s[1] = NEG_INF;
    if (mv0.z == 0) s[2] = NEG_INF;
    if (mv0.w == 0) s[3] = NEG_INF;
    if (mv1.x == 0) s[4] = NEG_INF;
    if (mv1.y == 0) s[5] = NEG_INF;
    if (mv1.z == 0) s[6] = NEG_INF;
    if (mv1.w == 0) s[7] = NEG_INF;

    float m = fmaxf(fmaxf(fmaxf(s[0], s[1]), fmaxf(s[2], s[3])),
                    fmaxf(fmaxf(s[4], s[5]), fmaxf(s[6], s[7])));

    __shared__ float red[256];
    red[t] = m;
    __syncthreads();
    for (int sw = 128; sw > 0; sw >>= 1) {
        if (t < sw) red[t] = fmaxf(red[t], red[t + sw]);
        __syncthreads();
    }
    const float mx = red[0];
    __syncthreads();

    float e[8];
#pragma unroll
    for (int j = 0; j < 8; ++j) e[j] = __expf(s[j] - mx);
    float s8 = ((e[0] + e[1]) + (e[2] + e[3])) + ((e[4] + e[5]) + (e[6] + e[7]));

    red[t] = s8;
    __syncthreads();
    for (int sw = 128; sw > 0; sw >>= 1) {
        if (t < sw) red[t] += red[t + sw];
        __syncthreads();
    }
    const float inv = 1.0f / red[0];

    ushort4 w0, w1;
    w0.x = f2bf(e[0] * inv); w0.y = f2bf(e[1] * inv);
    w0.z = f2bf(e[2] * inv); w0.w = f2bf(e[3] * inv);
    w1.x = f2bf(e[4] * inv); w1.y = f2bf(e[5] * inv);
    w1.z = f2bf(e[6] * inv); w1.w = f2bf(e[7] * inv);
    *(ushort4*)&pr[t * 8]     = w0;
    *(ushort4*)&pr[t * 8 + 4] = w1;
}

extern "C" void kernel_launch(void* const* d_in, const int* in_sizes, int n_in,
                              void* d_out, int out_size, void* d_ws, size_t ws_size,
                              hipStream_t stream)
{
    const float* x    = (const float*)d_in[0];
    const int*   mask = (const int*)d_in[1];
    const float* Wq   = (const float*)d_in[2];
    const float* bq   = (const float*)d_in[3];
    const float* Wk   = (const float*)d_in[4];
    const float* bk   = (const float*)d_in[5];
    const float* Wv   = (const float*)d_in[6];
    const float* bv   = (const float*)d_in[7];
    float* out = (float*)d_out;

    char* ws = (char*)d_ws;
    unsigned short* Q  = (unsigned short*)(ws);                  // [8][2048][1024] bf16, pre-scaled 1/32
    unsigned short* Kt = (unsigned short*)(ws + (32ull << 20));  // [8][2048][1024] bf16
    unsigned short* Vt = (unsigned short*)(ws + (64ull << 20));  // [8][1024][2048] bf16 (transposed)
    __half*         Sf = (__half*)(ws + (96ull << 20));          // [8][2048][2048] fp16 raw scores
    unsigned short* P  = (unsigned short*)(ws + (160ull << 20)); // [8][2048][2048] bf16 probs
    // overlays inside P region (dead before softmax writes P):
    unsigned short* xb = (unsigned short*)(ws + (160ull << 20)); // bf16 x (dead after projections)
    unsigned short* wb = (unsigned short*)(ws + (192ull << 20)); // bf16 weights [3072][1024]

    const int D = 1024, S = 2048, B = 8, Mtot = 16384;
    dim3 blk2(256), blk5(512);

    // ---- fp32 -> bf16 conversions (weights stacked -> [3072][1024]) ----
    conv_f32_bf16<<<dim3((Mtot * D / 4) / 256), blk2, 0, stream>>>((const float4*)x, (ushort4*)xb, Mtot * D / 4);
    conv_f32_bf16<<<dim3((D * D / 4) / 256), blk2, 0, stream>>>((const float4*)Wq, (ushort4*)(wb + 0ull * D * D), D * D / 4);
    conv_f32_bf16<<<dim3((D * D / 4) / 256), blk2, 0, stream>>>((const float4*)Wk, (ushort4*)(wb + 1ull * D * D), D * D / 4);
    conv_f32_bf16<<<dim3((D * D / 4) / 256), blk2, 0, stream>>>((const float4*)Wv, (ushort4*)(wb + 2ull * D * D), D * D / 4);

    // ---- fused QKV projection: [16384 x 3072] = xb @ wb^T (grid 64x12) ----
    gemm256<0><<<dim3(768), blk5, 0, stream>>>(
        xb, wb, Q, Kt, Vt, bq, bk, bv,
        D, 1024, 1024, 1024, 0, 0, 0, 64, 12);

    // ---- scores: S_b = Q_b @ K_b^T (scale folded into Q), fp16 out, no mask ----
    gemm256<1><<<dim3(512), blk5, 0, stream>>>(
        Q, Kt, Sf, nullptr, nullptr, nullptr, nullptr, nullptr,
        D, 1024, 1024, 2048, (long)S * D, (long)S * D, (long)S * S, 8, 8);

    // ---- softmax rows (fp16 in, mask applied, bf16 P out at stride 2048) ----
    softmax_rows<<<dim3(B * S), blk2, 0, stream>>>(Sf, mask, P);

    // ---- out: O_b = P_b @ V_b = P_b . Vt_b^T ----
    gemm256<2><<<dim3(256), blk5, 0, stream>>>(
        P, Vt, out, nullptr, nullptr, nullptr, nullptr, nullptr,
        S, 2048, 2048, 1024, (long)S * 2048, (long)D * S, (long)S * D, 8, 4);
}

// Round 8
// 266.254 us; speedup vs baseline: 1.1870x; 1.1264x over previous
//
#include <hip/hip_runtime.h>
#include <hip/hip_bf16.h>
#include <hip/hip_fp16.h>

#define NEG_INF -1000000000.0f

typedef __attribute__((ext_vector_type(8))) short bf16x8;
typedef __attribute__((ext_vector_type(4))) float f32x4;

__device__ __forceinline__ unsigned short f2bf(float f) {
    unsigned int u = __float_as_uint(f);
    u += 0x7FFFu + ((u >> 16) & 1u);
    return (unsigned short)(u >> 16);
}

__device__ __forceinline__ float h2f(unsigned short us) {
    __half h;
    __builtin_memcpy(&h, &us, 2);
    return __half2float(h);
}

#define GLOAD_LDS16(gp, lp)                                                  \
    __builtin_amdgcn_global_load_lds(                                        \
        (const __attribute__((address_space(1))) void*)(gp),                 \
        (__attribute__((address_space(3))) void*)(lp), 16, 0, 0)

// 256x256-tile BT-form bf16 GEMM, BK=64, 512 threads = 8 waves (2Mx4N),
// 4 phases per K-tile (2 barriers/phase), double-buffered 128 KiB LDS,
// counted-vmcnt pipeline (never 0 in main loop), T2 XOR swizzle, T5 setprio.
// C[m][n] = sum_k A[m][k]*B[n][k].
// EPI: 0 = Q projection (bf16 out, +bias, *1/32)
//      1 = scores compact (fp16 out; early-exit N-tiles >= ncp[bz])
//      2 = PV (fp32 out; runtime K = ncp[bz])
//      3 = KV projection, gathered A rows (early-exit M-tiles >= ncp[bz];
//          which=bn>>10: 0->Kc row-store, 1->Vtc transposed store)
template<int EPI>
__global__ __launch_bounds__(512, 2)
void gemm256(const unsigned short* __restrict__ A, const unsigned short* __restrict__ B,
             void* __restrict__ C0, void* __restrict__ C1,
             const float* __restrict__ b0, const float* __restrict__ b1,
             const int* __restrict__ cidx, const int* __restrict__ ncinfo,
             int K, long lda, long ldb, long ldc,
             long batchA, long batchB, long batchC,
             int gx, int gy)
{
    __shared__ unsigned short As[2][16384];
    __shared__ unsigned short Bs[2][16384];

    // T1: bijective XCD swizzle (all launched grids are % 8 == 0)
    int bid = blockIdx.x;
    bid = (bid & 7) * ((int)gridDim.x >> 3) + (bid >> 3);
    const int gxy = gx * gy;
    const int bz  = bid / gxy;
    const int rem = bid - bz * gxy;
    const int tm  = rem / gy;
    const int bm  = tm * 256;
    const int bn  = (rem - tm * gy) * 256;

    if (EPI == 3) { if (bm >= ncinfo[8 + bz]) return; }
    if (EPI == 1) { if (bn >= ncinfo[8 + bz]) return; }

    const int t    = threadIdx.x;
    const int lane = t & 63;
    const int w    = t >> 6;
    const int wr   = w >> 2;          // wave row 0..1 (128 rows each)
    const int wc   = w & 3;           // wave col 0..3 (64 cols each)
    const int lr   = lane & 15;
    const int lkg  = lane >> 4;       // 0..3
    const int sx8  = (lr & 7) * 8;    // T2 read-side XOR (row parity, elems)
    const int e0   = (lkg * 8) ^ sx8; // kk=0 chunk; kk=1 is e0^32

    // staging: thread t -> row tr (of 64-row load region), swizzled col chunk
    const int tr  = t >> 3;
    const int tcs = ((t & 7) ^ (tr & 7)) * 8;    // pre-swizzled source col (elems)
    const int wb512 = w * 512;                   // wave-uniform LDS elem offset

    const unsigned short* Ab = A + (size_t)bz * (size_t)batchA + (size_t)(bm + tr) * lda + tcs;
    const unsigned short* Bb = B + (size_t)bz * (size_t)batchB + (size_t)(bn + tr) * ldb + tcs;

    // per-L A row base pointers (gathered for EPI==3, linear otherwise)
    const unsigned short* ApG[4];
#pragma unroll
    for (int L = 0; L < 4; ++L) {
        if (EPI == 3) {
            const int rr = cidx[bz * 2048 + bm + L * 64 + tr];
            ApG[L] = A + ((size_t)bz * 2048 + rr) * lda + tcs;
        } else {
            ApG[L] = Ab + (size_t)L * 64 * lda;
        }
    }

    const int Kd = (EPI == 2) ? ncinfo[8 + bz] : K;

#define ST_A(nb, L, kt) GLOAD_LDS16(ApG[L] + (kt), &As[nb][(L) * 4096 + wb512])
#define ST_B(nb, L, kt) GLOAD_LDS16(Bb + (size_t)(L) * 64 * ldb + (kt), &Bs[nb][(L) * 4096 + wb512])

    f32x4 acc[8][4];
#pragma unroll
    for (int i = 0; i < 8; ++i)
#pragma unroll
        for (int j = 0; j < 4; ++j)
            acc[i][j] = f32x4{0.f, 0.f, 0.f, 0.f};

    // ---- prologue: stage tile 0 (needed-first order), leave A1,A3 in flight ----
    ST_B(0, 0, 0); ST_B(0, 1, 0); ST_B(0, 2, 0); ST_B(0, 3, 0);
    ST_A(0, 0, 0); ST_A(0, 2, 0); ST_A(0, 1, 0); ST_A(0, 3, 0);
    asm volatile("s_waitcnt vmcnt(2)" ::: "memory");
    __builtin_amdgcn_s_barrier();

    bf16x8 a[2][2], b[4][2];

#define READ_B(BUF)                                                          \
    _Pragma("unroll") for (int j = 0; j < 4; ++j) {                          \
        const int Rb = wc * 64 + j * 16 + lr;                                \
        b[j][0] = *(const bf16x8*)&Bs[BUF][Rb * 64 + e0];                    \
        b[j][1] = *(const bf16x8*)&Bs[BUF][Rb * 64 + (e0 ^ 32)];             \
    }

#define LOAD_A(BUF, qp)                                                      \
    _Pragma("unroll") for (int i2 = 0; i2 < 2; ++i2) {                       \
        const int Ra = wr * 128 + (qp) * 32 + i2 * 16 + lr;                  \
        a[i2][0] = *(const bf16x8*)&As[BUF][Ra * 64 + e0];                   \
        a[i2][1] = *(const bf16x8*)&As[BUF][Ra * 64 + (e0 ^ 32)];            \
    }

#define MFMA_Q(qp)                                                           \
    __builtin_amdgcn_s_setprio(1);                                           \
    _Pragma("unroll") for (int kk = 0; kk < 2; ++kk)                         \
    _Pragma("unroll") for (int i2 = 0; i2 < 2; ++i2)                         \
    _Pragma("unroll") for (int j = 0; j < 4; ++j)                            \
        acc[(qp) * 2 + i2][j] = __builtin_amdgcn_mfma_f32_16x16x32_bf16(     \
            a[i2][kk], b[j][kk], acc[(qp) * 2 + i2][j], 0, 0, 0);            \
    __builtin_amdgcn_s_setprio(0);

#define TILE(BUF, STAGE, ktn)                                                \
    {                                                                        \
        const int buf_ = (BUF); const int nb_ = buf_ ^ 1;                    \
        /* phase 0: B-frags (whole tile) + A quad 0; stage B0,B1 of next */  \
        READ_B(buf_)                                                         \
        LOAD_A(buf_, 0)                                                      \
        if (STAGE) { ST_B(nb_, 0, ktn); ST_B(nb_, 1, ktn); }                 \
        __builtin_amdgcn_s_barrier();                                        \
        MFMA_Q(0)                                                            \
        __builtin_amdgcn_s_barrier();                                        \
        /* phase 1 */                                                        \
        LOAD_A(buf_, 1)                                                      \
        if (STAGE) { ST_B(nb_, 2, ktn); ST_B(nb_, 3, ktn); }                 \
        __builtin_amdgcn_s_barrier();                                        \
        MFMA_Q(1)                                                            \
        if (STAGE) { asm volatile("s_waitcnt vmcnt(4)" ::: "memory"); }      \
        else       { asm volatile("s_waitcnt vmcnt(0)" ::: "memory"); }      \
        __builtin_amdgcn_s_barrier();                                        \
        /* phase 2 */                                                        \
        LOAD_A(buf_, 2)                                                      \
        if (STAGE) { ST_A(nb_, 0, ktn); ST_A(nb_, 2, ktn); }                 \
        __builtin_amdgcn_s_barrier();                                        \
        MFMA_Q(2)                                                            \
        __builtin_amdgcn_s_barrier();                                        \
        /* phase 3 */                                                        \
        LOAD_A(buf_, 3)                                                      \
        if (STAGE) { ST_A(nb_, 1, ktn); ST_A(nb_, 3, ktn); }                 \
        __builtin_amdgcn_s_barrier();                                        \
        MFMA_Q(3)                                                            \
        if (STAGE) { asm volatile("s_waitcnt vmcnt(2)" ::: "memory"); }      \
        __builtin_amdgcn_s_barrier();                                        \
    }

    const int NT = Kd >> 6;
    for (int k = 0; k < NT - 1; ++k) {
        TILE(k & 1, true, (k + 1) << 6);
    }
    TILE((NT - 1) & 1, false, 0);

#undef TILE
#undef MFMA_Q
#undef LOAD_A
#undef READ_B
#undef ST_A
#undef ST_B

    // ---- epilogue ----  C/D: col = lane&15 (lr), row = lkg*4 + reg
    const int r0 = lkg * 4;
    const size_t coff = (size_t)bz * (size_t)batchC;
#pragma unroll
    for (int ri = 0; ri < 8; ++ri) {
#pragma unroll
        for (int j = 0; j < 4; ++j) {
            if (EPI == 0) {
                const int gcol = bn + wc * 64 + j * 16 + lr;
                const float bv = b0[gcol];
#pragma unroll
                for (int r = 0; r < 4; ++r) {
                    const int grow = bm + wr * 128 + ri * 16 + r0 + r;
                    ((unsigned short*)C0)[(size_t)grow * ldc + gcol] =
                        f2bf((acc[ri][j][r] + bv) * 0.03125f);
                }
            } else if (EPI == 3) {
                const int gcol3 = bn + wc * 64 + j * 16 + lr;
                const int which = gcol3 >> 10;            // block-uniform: 0=K,1=V
                const int col   = gcol3 & 1023;
                const float bv  = (which == 0) ? b0[col] : b1[col];
                if (which == 0) {
                    // Kc[bz][row][col]
                    unsigned short* dst = (unsigned short*)C0 + (size_t)bz * (2048 * 1024);
#pragma unroll
                    for (int r = 0; r < 4; ++r) {
                        const int grow = bm + wr * 128 + ri * 16 + r0 + r;
                        dst[(size_t)grow * 1024 + col] = f2bf(acc[ri][j][r] + bv);
                    }
                } else {
                    // Vtc[bz][col][row] (transposed, rows contiguous in reg quad)
                    const int m0 = bm + wr * 128 + ri * 16 + r0;
                    ushort4 wv;
                    wv.x = f2bf(acc[ri][j][0] + bv);
                    wv.y = f2bf(acc[ri][j][1] + bv);
                    wv.z = f2bf(acc[ri][j][2] + bv);
                    wv.w = f2bf(acc[ri][j][3] + bv);
                    *(ushort4*)((unsigned short*)C1 + (size_t)bz * (1024 * 2048)
                                + (size_t)col * 2048 + m0) = wv;
                }
            } else if (EPI == 1) {
                const int gcol = bn + wc * 64 + j * 16 + lr;
#pragma unroll
                for (int r = 0; r < 4; ++r) {
                    const int grow = bm + wr * 128 + ri * 16 + r0 + r;
                    ((__half*)C0)[coff + (size_t)grow * ldc + gcol] =
                        __float2half(acc[ri][j][r]);
                }
            } else {
                const int gcol = bn + wc * 64 + j * 16 + lr;
#pragma unroll
                for (int r = 0; r < 4; ++r) {
                    const int grow = bm + wr * 128 + ri * 16 + r0 + r;
                    ((float*)C0)[coff + (size_t)grow * ldc + gcol] = acc[ri][j][r];
                }
            }
        }
    }
}

// fp32 -> bf16 conversion, 4 elems/thread
__global__ __launch_bounds__(256)
void conv_f32_bf16(const float4* __restrict__ src, ushort4* __restrict__ dst, int n4)
{
    const int i = blockIdx.x * 256 + threadIdx.x;
    if (i < n4) {
        const float4 v = src[i];
        ushort4 wv;
        wv.x = f2bf(v.x); wv.y = f2bf(v.y); wv.z = f2bf(v.z); wv.w = f2bf(v.w);
        dst[i] = wv;
    }
}

// Per-batch stable compaction of unmasked key positions.
// cidx[b][j] = s-index of j-th unmasked key; pads (nc..ncp) -> 0.
// ncinfo[b] = nc, ncinfo[8+b] = ncp (nc rounded up to 256, min 256).
__global__ __launch_bounds__(256)
void compact_mask(const int* __restrict__ mask, int* __restrict__ cidx,
                  int* __restrict__ ncinfo)
{
    const int b = blockIdx.x;
    const int t = threadIdx.x;
    const int* mb = mask + b * 2048;
    int loc[8];
    int c = 0;
#pragma unroll
    for (int j = 0; j < 8; ++j) {
        const int s = t * 8 + j;
        if (mb[s] != 0) loc[c++] = s;
    }
    __shared__ int ps[256];
    ps[t] = c;
    __syncthreads();
    for (int off = 1; off < 256; off <<= 1) {
        const int v = (t >= off) ? ps[t - off] : 0;
        __syncthreads();
        ps[t] += v;
        __syncthreads();
    }
    const int base = ps[t] - c;
    int* cb = cidx + b * 2048;
    for (int i = 0; i < c; ++i) cb[base + i] = loc[i];
    __syncthreads();
    const int nc  = ps[255];
    int ncp = (nc + 255) & ~255;
    if (ncp < 256) ncp = 256;
    for (int i = nc + t; i < ncp; i += 256) cb[i] = 0;
    if (t == 0) { ncinfo[b] = nc; ncinfo[8 + b] = ncp; }
}

// Row softmax over compacted scores, IN-PLACE: fp16 scores in (cols < nc
// valid), bf16 P out to the SAME buffer (cols < ncp; pads [nc,ncp) get 0).
// Each thread reads and rewrites only its own 8 columns -> race-free.
// Normalizing over unmasked cols only is exact: reference's masked terms are
// exp(-1e9-mx) == 0 in fp32.
__global__ __launch_bounds__(256)
void softmax_rows(unsigned short* __restrict__ SP, const int* __restrict__ ncinfo)
{
    const size_t row = blockIdx.x;          // b*2048 + q
    const int b   = (int)(row >> 11);
    const int nc  = ncinfo[b];
    const int ncp = ncinfo[8 + b];
    unsigned short* sp = SP + row * 2048;
    const int t  = threadIdx.x;
    const int c0 = t * 8;
    const bool act = c0 < ncp;

    float s[8];
#pragma unroll
    for (int j = 0; j < 8; ++j) s[j] = NEG_INF;
    if (act) {
        const ushort4 h0 = *(const ushort4*)&sp[c0];
        const ushort4 h1 = *(const ushort4*)&sp[c0 + 4];
        const unsigned short hv[8] = {h0.x, h0.y, h0.z, h0.w, h1.x, h1.y, h1.z, h1.w};
#pragma unroll
        for (int j = 0; j < 8; ++j)
            if (c0 + j < nc) s[j] = h2f(hv[j]);
    }

    float m = fmaxf(fmaxf(fmaxf(s[0], s[1]), fmaxf(s[2], s[3])),
                    fmaxf(fmaxf(s[4], s[5]), fmaxf(s[6], s[7])));

    __shared__ float red[256];
    red[t] = m;
    __syncthreads();
    for (int sw = 128; sw > 0; sw >>= 1) {
        if (t < sw) red[t] = fmaxf(red[t], red[t + sw]);
        __syncthreads();
    }
    const float mx = red[0];
    __syncthreads();

    float e[8];
#pragma unroll
    for (int j = 0; j < 8; ++j) e[j] = __expf(s[j] - mx);
    float s8 = ((e[0] + e[1]) + (e[2] + e[3])) + ((e[4] + e[5]) + (e[6] + e[7]));

    red[t] = s8;
    __syncthreads();
    for (int sw = 128; sw > 0; sw >>= 1) {
        if (t < sw) red[t] += red[t + sw];
        __syncthreads();
    }
    const float inv = 1.0f / red[0];

    if (act) {
        ushort4 w0, w1;
        w0.x = f2bf(e[0] * inv); w0.y = f2bf(e[1] * inv);
        w0.z = f2bf(e[2] * inv); w0.w = f2bf(e[3] * inv);
        w1.x = f2bf(e[4] * inv); w1.y = f2bf(e[5] * inv);
        w1.z = f2bf(e[6] * inv); w1.w = f2bf(e[7] * inv);
        *(ushort4*)&sp[c0]     = w0;
        *(ushort4*)&sp[c0 + 4] = w1;
    }
}

extern "C" void kernel_launch(void* const* d_in, const int* in_sizes, int n_in,
                              void* d_out, int out_size, void* d_ws, size_t ws_size,
                              hipStream_t stream)
{
    const float* x    = (const float*)d_in[0];
    const int*   mask = (const int*)d_in[1];
    const float* Wq   = (const float*)d_in[2];
    const float* bq   = (const float*)d_in[3];
    const float* Wk   = (const float*)d_in[4];
    const float* bk   = (const float*)d_in[5];
    const float* Wv   = (const float*)d_in[6];
    const float* bv   = (const float*)d_in[7];
    float* out = (float*)d_out;

    // Workspace layout (max 199 MiB + 64 B; NO overlaps among live ranges):
    //   [0,32)    Q       [16384][1024] bf16 (pre-scaled 1/32)
    //   [32,64)   Kc      [8][2048][1024] bf16 compacted keys (rows < ncp valid)
    //   [64,96)   Vtc     [8][1024][2048] bf16 compacted V^T (cols < ncp valid)
    //   [96,160)  Sf/P    [8][2048][2048] fp16 scores -> bf16 probs IN-PLACE
    //   [160,192) xb      bf16 x (dead after KV projection)
    //   [192,198) wb      bf16 weights [3072][1024]
    //   [198,199) cidx    [8][2048] int
    //   [199,..)  ncinfo  [16] int
    char* ws = (char*)d_ws;
    unsigned short* Q   = (unsigned short*)(ws);
    unsigned short* Kc  = (unsigned short*)(ws + (32ull << 20));
    unsigned short* Vtc = (unsigned short*)(ws + (64ull << 20));
    unsigned short* SP  = (unsigned short*)(ws + (96ull << 20));
    unsigned short* xb  = (unsigned short*)(ws + (160ull << 20));
    unsigned short* wb  = (unsigned short*)(ws + (192ull << 20));
    int*            cidx   = (int*)(ws + (198ull << 20));
    int*            ncinfo = (int*)(ws + (199ull << 20));

    const int D = 1024, S = 2048, B = 8, Mtot = 16384;
    dim3 blk2(256), blk5(512);

    // ---- fp32 -> bf16 conversions (weights stacked -> [3072][1024]) ----
    conv_f32_bf16<<<dim3((Mtot * D / 4) / 256), blk2, 0, stream>>>((const float4*)x, (ushort4*)xb, Mtot * D / 4);
    conv_f32_bf16<<<dim3((D * D / 4) / 256), blk2, 0, stream>>>((const float4*)Wq, (ushort4*)(wb + 0ull * D * D), D * D / 4);
    conv_f32_bf16<<<dim3((D * D / 4) / 256), blk2, 0, stream>>>((const float4*)Wk, (ushort4*)(wb + 1ull * D * D), D * D / 4);
    conv_f32_bf16<<<dim3((D * D / 4) / 256), blk2, 0, stream>>>((const float4*)Wv, (ushort4*)(wb + 2ull * D * D), D * D / 4);

    // ---- mask compaction ----
    compact_mask<<<dim3(B), blk2, 0, stream>>>(mask, cidx, ncinfo);

    // ---- Q projection: [16384 x 1024] = xb @ Wq^T (+bq)*1/32 ----
    gemm256<0><<<dim3(256), blk5, 0, stream>>>(
        xb, wb, Q, nullptr, bq, nullptr, nullptr, nullptr,
        D, 1024, 1024, 1024, 0, 0, 0, 64, 4);

    // ---- KV projection on compacted rows: [ncp_b x 2048] per batch ----
    gemm256<3><<<dim3(512), blk5, 0, stream>>>(
        xb, wb + 1ull * D * D, Kc, Vtc, bk, bv, cidx, ncinfo,
        D, 1024, 1024, 1024, 0, 0, 0, 8, 8);

    // ---- scores: S_b = Q_b @ Kc_b^T (scale folded into Q), fp16 out ----
    gemm256<1><<<dim3(512), blk5, 0, stream>>>(
        Q, Kc, SP, nullptr, nullptr, nullptr, nullptr, ncinfo,
        D, 1024, 1024, 2048, (long)S * D, (long)S * D, (long)S * S, 8, 8);

    // ---- softmax over compacted cols, in-place (bf16 P out, pads = 0) ----
    softmax_rows<<<dim3(B * S), blk2, 0, stream>>>(SP, ncinfo);

    // ---- out: O_b = P_b @ Vc_b = P_b . Vtc_b^T (runtime K = ncp_b) ----
    gemm256<2><<<dim3(256), blk5, 0, stream>>>(
        SP, Vtc, out, nullptr, nullptr, nullptr, nullptr, ncinfo,
        S, 2048, 2048, 1024, (long)S * 2048, (long)D * S, (long)S * D, 8, 4);
}